// Round 4
// baseline (167.182 us; speedup 1.0000x reference)
//
#include <hip/hip_runtime.h>
#include <stdint.h>

#define TPB 256
#define SELTPB 1024
#define SELWAVES (SELTPB / 64)
#define MAXNO 64

__device__ __forceinline__ float sl1f(float d) {
    float ad = fabsf(d);
    return ad < 1.0f ? 0.5f * d * d : ad - 0.5f;
}

__device__ __forceinline__ float iou_pair(float tx1, float ty1, float tx2, float ty2, float ta,
                                          float px1, float py1, float px2, float py2, float pa) {
    float ltx = fmaxf(tx1, px1), lty = fmaxf(ty1, py1);
    float rbx = fminf(tx2, px2), rby = fminf(ty2, py2);
    float wx = fmaxf(rbx - ltx, 0.0f), wy = fmaxf(rby - lty, 0.0f);
    float inter = wx * wy;
    return inter / ((ta + pa) - inter);
}

// Kernel A: one block per batch row; computes per-truth argmax over ALL priors
// with register running-max + wave reduce + LDS combine. Writes keys directly:
// key = (float_bits(iou) << 32) | (0xFFFFFFFF - p)  => max iou, tie -> min p.
// No atomics, no zero-init needed (replaces the pathologically slow 16KB fill).
template <int NO, int BS>
__global__ __launch_bounds__(BS) void match_kernel(
    const float* __restrict__ dbox, const float* __restrict__ targets,
    unsigned long long* __restrict__ keys, int Np, int No) {
    constexpr int NW = BS / 64;
    int b = blockIdx.x;
    int tid = threadIdx.x;
    __shared__ float s_t[NO][5];  // x1,y1,x2,y2,area
    __shared__ unsigned long long s_k[NW][NO];
    if (tid < No) {
        const float* tr = targets + ((size_t)b * No + tid) * 5;
        float x1 = tr[0], y1 = tr[1], x2 = tr[2], y2 = tr[3];
        s_t[tid][0] = x1; s_t[tid][1] = y1; s_t[tid][2] = x2; s_t[tid][3] = y2;
        s_t[tid][4] = (x2 - x1) * (y2 - y1);
    }
    __syncthreads();
    unsigned long long key[NO];
#pragma unroll
    for (int t = 0; t < NO; ++t) key[t] = 0ull;
    for (int p = tid; p < Np; p += BS) {
        float4 pr = *reinterpret_cast<const float4*>(dbox + (size_t)p * 4);
        float px1 = pr.x - pr.z * 0.5f, py1 = pr.y - pr.w * 0.5f;
        float px2 = pr.x + pr.z * 0.5f, py2 = pr.y + pr.w * 0.5f;
        float pa = (px2 - px1) * (py2 - py1);
        unsigned lowp = 0xFFFFFFFFu - (unsigned)p;
#pragma unroll
        for (int t = 0; t < NO; ++t) {
            if (NO > 16 && t >= No) break;  // generic fallback path only
            float iou = iou_pair(s_t[t][0], s_t[t][1], s_t[t][2], s_t[t][3], s_t[t][4],
                                 px1, py1, px2, py2, pa);
            unsigned long long k =
                (((unsigned long long)__float_as_uint(iou)) << 32) | (unsigned long long)lowp;
            if (k > key[t]) key[t] = k;
        }
    }
    int lane = tid & 63, wv = tid >> 6;
#pragma unroll
    for (int t = 0; t < NO; ++t) {
        if (NO > 16 && t >= No) break;
        unsigned long long k = key[t];
        for (int off = 32; off; off >>= 1) {
            unsigned long long o = __shfl_down(k, off);
            if (o > k) k = o;
        }
        if (lane == 0) s_k[wv][t] = k;
    }
    __syncthreads();
    if (tid < No) {
        unsigned long long m = s_k[0][tid];
#pragma unroll
        for (int w = 1; w < NW; ++w)
            if (s_k[w][tid] > m) m = s_k[w][tid];
        keys[(size_t)b * No + tid] = m;
    }
}

// Kernel B (main): per prior -> recompute best-truth match, apply override, CE via
// log-softmax from LDS-staged conf row, smooth-L1 for positives, write v=loss_c_hnm.
__global__ __launch_bounds__(TPB) void main_kernel(
    const float* __restrict__ loc, const float* __restrict__ conf,
    const float* __restrict__ dbox, const float* __restrict__ targets,
    const unsigned long long* __restrict__ keys,
    float* __restrict__ v, float* __restrict__ part_l, float* __restrict__ part_c,
    int* __restrict__ part_n, int Np, int C, int No, int nchunk) {
    extern __shared__ float s_conf[];  // TPB * C
    __shared__ float s_t[MAXNO][5];
    __shared__ float s_lab[MAXNO];
    __shared__ int s_ovr[MAXNO];
    __shared__ float s_red1[4];
    __shared__ float s_red2[4];
    __shared__ int s_redi[4];
    int b = blockIdx.y, chunk = blockIdx.x, tid = threadIdx.x;
    int p = chunk * TPB + tid;
    bool valid = p < Np;
    if (tid < No) {
        const float* tr = targets + ((size_t)b * No + tid) * 5;
        float x1 = tr[0], y1 = tr[1], x2 = tr[2], y2 = tr[3];
        s_t[tid][0] = x1; s_t[tid][1] = y1; s_t[tid][2] = x2; s_t[tid][3] = y2;
        s_t[tid][4] = (x2 - x1) * (y2 - y1);
        s_lab[tid] = tr[4];
        unsigned long long k = keys[(size_t)b * No + tid];
        s_ovr[tid] = (int)(0xFFFFFFFFu - (unsigned)(k & 0xFFFFFFFFull));
    }
    int pbase = chunk * TPB;
    int cnt = Np - pbase;
    if (cnt > TPB) cnt = TPB;
    const float* cbase = conf + ((size_t)b * Np + (size_t)pbase) * C;
    for (int i = tid; i < cnt * C; i += TPB) s_conf[i] = cbase[i];
    __syncthreads();

    float lossl = 0.0f, posce = 0.0f;
    int npos = 0;
    if (valid) {
        float4 pr = *reinterpret_cast<const float4*>(dbox + (size_t)p * 4);
        float px1 = pr.x - pr.z * 0.5f, py1 = pr.y - pr.w * 0.5f;
        float px2 = pr.x + pr.z * 0.5f, py2 = pr.y + pr.w * 0.5f;
        float pa = (px2 - px1) * (py2 - py1);
        float bov = -1.0f;
        int bidx = 0;
        for (int t = 0; t < No; ++t) {
            float iou = iou_pair(s_t[t][0], s_t[t][1], s_t[t][2], s_t[t][3], s_t[t][4],
                                 px1, py1, px2, py2, pa);
            if (iou > bov) { bov = iou; bidx = t; }  // strict > : first occurrence
        }
        // override: ascending t, last wins (matches sequential duplicate scatter)
        for (int t = 0; t < No; ++t)
            if (s_ovr[t] == p) { bidx = t; bov = 2.0f; }
        int ct = (bov < 0.5f) ? 0 : ((int)s_lab[bidx] + 1);
        const float* crow = s_conf + (size_t)tid * C;
        float mx = crow[0];
        for (int j = 1; j < C; ++j) mx = fmaxf(mx, crow[j]);
        float s = 0.0f;
        for (int j = 0; j < C; ++j) s += expf(crow[j] - mx);
        float ce = logf(s) + mx - crow[ct];
        bool pos = ct > 0;
        v[(size_t)b * Np + p] = pos ? 0.0f : ce;
        if (pos) {
            posce = ce;
            npos = 1;
            float mx1 = s_t[bidx][0], my1 = s_t[bidx][1], mx2 = s_t[bidx][2], my2 = s_t[bidx][3];
            float gcx = ((mx1 + mx2) * 0.5f - pr.x) / (0.1f * pr.z);
            float gcy = ((my1 + my2) * 0.5f - pr.y) / (0.1f * pr.w);
            float gw = logf((mx2 - mx1) / pr.z) / 0.2f;
            float gh = logf((my2 - my1) / pr.w) / 0.2f;
            float4 l4 = *reinterpret_cast<const float4*>(loc + ((size_t)b * Np + p) * 4);
            lossl = sl1f(l4.x - gcx) + sl1f(l4.y - gcy) + sl1f(l4.z - gw) + sl1f(l4.w - gh);
        }
    }
    // single fused fixed-order block reduction (deterministic)
    float a1 = lossl, a2 = posce;
    int ni = npos;
    for (int off = 32; off; off >>= 1) {
        a1 += __shfl_down(a1, off);
        a2 += __shfl_down(a2, off);
        ni += __shfl_down(ni, off);
    }
    if ((tid & 63) == 0) {
        s_red1[tid >> 6] = a1;
        s_red2[tid >> 6] = a2;
        s_redi[tid >> 6] = ni;
    }
    __syncthreads();
    if (tid == 0) {
        part_l[(size_t)b * nchunk + chunk] = s_red1[0] + s_red1[1] + s_red1[2] + s_red1[3];
        part_c[(size_t)b * nchunk + chunk] = s_red2[0] + s_red2[1] + s_red2[2] + s_red2[3];
        part_n[(size_t)b * nchunk + chunk] = s_redi[0] + s_redi[1] + s_redi[2] + s_redi[3];
    }
}

// Kernel C: per row b -- radix-select the K-th largest float-bits threshold over v,
// then loss_c = posce + sum_{v > T} v + Krem * T.
__global__ __launch_bounds__(SELTPB) void select_kernel(
    const float* __restrict__ v, const float* __restrict__ pl,
    const float* __restrict__ pc, const int* __restrict__ pn,
    float* __restrict__ row_res, int Np, int nchunk, int negpos) {
    int b = blockIdx.x, tid = threadIdx.x;
    int lane = tid & 63, wv = tid >> 6;
    extern __shared__ unsigned sv[];  // Np
    __shared__ unsigned whist[SELWAVES][256];  // per-wave privatized hist (16 KB)
    __shared__ unsigned suf[257];
    __shared__ float s_f[SELWAVES];
    __shared__ int s_dig, s_acc;
    __shared__ float s_lossl, s_posce;
    __shared__ int s_np;

    if (wv == 0) {
        float a = 0.0f, c = 0.0f;
        int n = 0;
        for (int i = lane; i < nchunk; i += 64) {
            a += pl[(size_t)b * nchunk + i];
            c += pc[(size_t)b * nchunk + i];
            n += pn[(size_t)b * nchunk + i];
        }
        for (int off = 32; off; off >>= 1) {
            a += __shfl_down(a, off);
            c += __shfl_down(c, off);
            n += __shfl_down(n, off);
        }
        if (lane == 0) { s_lossl = a; s_posce = c; s_np = n; }
    }
    {
        const float4* v4 = reinterpret_cast<const float4*>(v + (size_t)b * Np);
        int n4 = Np >> 2;
        for (int i = tid; i < n4; i += SELTPB) {
            float4 f = v4[i];
            uint4 u;
            u.x = __float_as_uint(f.x); u.y = __float_as_uint(f.y);
            u.z = __float_as_uint(f.z); u.w = __float_as_uint(f.w);
            *reinterpret_cast<uint4*>(&sv[i << 2]) = u;
        }
        for (int i = (n4 << 2) + tid; i < Np; i += SELTPB)
            sv[i] = __float_as_uint(v[(size_t)b * Np + i]);
    }
    __syncthreads();
    int npos = s_np;
    int K = npos * negpos;
    if (K > Np) K = Np;
    float lossc = s_posce;
    if (K > 0) {
        unsigned prefix = 0;
        int Krem = K;
        for (int shift = 24; shift >= 0; shift -= 8) {
            for (int i = tid; i < SELWAVES * 256; i += SELTPB)
                (&whist[0][0])[i] = 0;
            __syncthreads();
            for (int i = tid; i < Np; i += SELTPB) {
                unsigned u = sv[i];
                bool match = (shift == 24) || ((u >> (shift + 8)) == (prefix >> (shift + 8)));
                if (match) atomicAdd(&whist[wv][(u >> shift) & 0xFFu], 1u);
            }
            __syncthreads();
            if (tid < 256) {
                unsigned t = 0;
                for (int w = 0; w < SELWAVES; ++w) t += whist[w][tid];
                suf[tid] = t;
            }
            if (tid == 0) suf[256] = 0;
            __syncthreads();
            for (int off = 1; off < 256; off <<= 1) {
                unsigned add = 0;
                if (tid < 256 && tid + off < 256) add = suf[tid + off];
                __syncthreads();
                if (tid < 256) suf[tid] += add;
                __syncthreads();
            }
            if (tid < 256) {
                unsigned S = suf[tid];
                unsigned Snext = suf[tid + 1];
                if ((int)S >= Krem && (int)Snext < Krem) { s_dig = tid; s_acc = (int)Snext; }
            }
            __syncthreads();
            prefix |= ((unsigned)s_dig) << shift;
            Krem -= s_acc;
            __syncthreads();
        }
        float sum_gt = 0.0f;
        for (int i = tid; i < Np; i += SELTPB) {
            unsigned u = sv[i];
            if (u > prefix) sum_gt += __uint_as_float(u);
        }
        for (int off = 32; off; off >>= 1) sum_gt += __shfl_down(sum_gt, off);
        if (lane == 0) s_f[wv] = sum_gt;
        __syncthreads();
        if (tid == 0) {
            float t = 0.0f;
            for (int w = 0; w < SELWAVES; ++w) t += s_f[w];
            lossc += t + (float)Krem * __uint_as_float(prefix);
        }
    }
    if (tid == 0) {
        row_res[(size_t)b * 3 + 0] = s_lossl;
        row_res[(size_t)b * 3 + 1] = lossc;
        row_res[(size_t)b * 3 + 2] = (float)npos;
    }
}

__global__ __launch_bounds__(TPB) void finalize_kernel(
    const float* __restrict__ row_res, float* __restrict__ out, int B) {
    int tid = threadIdx.x;
    float l = 0, c = 0, n = 0;
    for (int i = tid; i < B; i += TPB) {
        l += row_res[(size_t)i * 3 + 0];
        c += row_res[(size_t)i * 3 + 1];
        n += row_res[(size_t)i * 3 + 2];
    }
    __shared__ float sl[4], sc[4], sn[4];
    for (int off = 32; off; off >>= 1) {
        l += __shfl_down(l, off);
        c += __shfl_down(c, off);
        n += __shfl_down(n, off);
    }
    int lane = tid & 63, w = tid >> 6;
    if (lane == 0) { sl[w] = l; sc[w] = c; sn[w] = n; }
    __syncthreads();
    if (tid == 0) {
        l = sl[0] + sl[1] + sl[2] + sl[3];
        c = sc[0] + sc[1] + sc[2] + sc[3];
        n = sn[0] + sn[1] + sn[2] + sn[3];
        out[0] = l / n;
        out[1] = c / n;
    }
}

extern "C" void kernel_launch(void* const* d_in, const int* in_sizes, int n_in,
                              void* d_out, int out_size, void* d_ws, size_t ws_size,
                              hipStream_t stream) {
    const float* loc = (const float*)d_in[0];
    const float* conf = (const float*)d_in[1];
    const float* dbox = (const float*)d_in[2];
    const float* targets = (const float*)d_in[3];

    int Np = in_sizes[2] / 4;
    int B = in_sizes[0] / (Np * 4);
    int C = in_sizes[1] / (B * Np);
    int No = in_sizes[3] / (B * 5);
    int nchunk = (Np + TPB - 1) / TPB;

    char* w = (char*)d_ws;
    unsigned long long* keys = (unsigned long long*)w;
    w += (size_t)B * No * sizeof(unsigned long long);
    float* v = (float*)w;
    w += (size_t)B * Np * sizeof(float);
    float* part_l = (float*)w;
    w += (size_t)B * nchunk * sizeof(float);
    float* part_c = (float*)w;
    w += (size_t)B * nchunk * sizeof(float);
    int* part_n = (int*)w;
    w += (size_t)B * nchunk * sizeof(int);
    float* row_res = (float*)w;

    if (No == 16)
        match_kernel<16, 1024><<<B, 1024, 0, stream>>>(dbox, targets, keys, Np, No);
    else
        match_kernel<MAXNO, 256><<<B, 256, 0, stream>>>(dbox, targets, keys, Np, No);

    dim3 grid(nchunk, B);
    size_t lds_main = (size_t)TPB * C * sizeof(float);
    main_kernel<<<grid, TPB, lds_main, stream>>>(loc, conf, dbox, targets, keys,
                                                 v, part_l, part_c, part_n, Np, C, No, nchunk);
    select_kernel<<<B, SELTPB, (size_t)Np * sizeof(float), stream>>>(v, part_l, part_c, part_n,
                                                                     row_res, Np, nchunk, 3);
    finalize_kernel<<<1, TPB, 0, stream>>>(row_res, (float*)d_out, B);
}

// Round 5
// 87.025 us; speedup vs baseline: 1.9211x; 1.9211x over previous
//
#include <hip/hip_runtime.h>
#include <stdint.h>

#define TPB 256
#define SELTPB 1024
#define SELWAVES (SELTPB / 64)
#define MAXNO 64
#define NMB 4  // match chunks per batch row

__device__ __forceinline__ float sl1f(float d) {
    float ad = fabsf(d);
    return ad < 1.0f ? 0.5f * d * d : ad - 0.5f;
}

__device__ __forceinline__ float iou_pair(float tx1, float ty1, float tx2, float ty2, float ta,
                                          float px1, float py1, float px2, float py2, float pa) {
    float ltx = fmaxf(tx1, px1), lty = fmaxf(ty1, py1);
    float rbx = fminf(tx2, px2), rby = fminf(ty2, py2);
    float wx = fmaxf(rbx - ltx, 0.0f), wy = fmaxf(rby - lty, 0.0f);
    float inter = wx * wy;
    return inter / ((ta + pa) - inter);
}

// Kernel A: per (b, chunk) partial argmax over that chunk's priors.
// key = (float_bits(iou) << 32) | (0xFFFFFFFF - p)  => max iou, tie -> min p.
// 256 threads (no VGPR cap -> key[16] stays in registers), register running max,
// wave reduce + LDS combine, direct store of partials. No atomics, no zero-init.
// Final max over the NMB partials is folded into main_kernel.
template <int NO>
__global__ __launch_bounds__(256) void match_partial_kernel(
    const float* __restrict__ dbox, const float* __restrict__ targets,
    unsigned long long* __restrict__ pkeys, int Np, int No) {
    int b = blockIdx.y, mb = blockIdx.x;
    int tid = threadIdx.x;
    __shared__ float s_t[NO][5];  // x1,y1,x2,y2,area
    __shared__ unsigned long long s_k[4][NO];
    if (tid < No) {
        const float* tr = targets + ((size_t)b * No + tid) * 5;
        float x1 = tr[0], y1 = tr[1], x2 = tr[2], y2 = tr[3];
        s_t[tid][0] = x1; s_t[tid][1] = y1; s_t[tid][2] = x2; s_t[tid][3] = y2;
        s_t[tid][4] = (x2 - x1) * (y2 - y1);
    }
    __syncthreads();
    int clen = (Np + NMB - 1) / NMB;
    int start = mb * clen;
    int end = start + clen;
    if (end > Np) end = Np;
    unsigned long long key[NO];
#pragma unroll
    for (int t = 0; t < NO; ++t) key[t] = 0ull;
    for (int p = start + tid; p < end; p += 256) {
        float4 pr = *reinterpret_cast<const float4*>(dbox + (size_t)p * 4);
        float px1 = pr.x - pr.z * 0.5f, py1 = pr.y - pr.w * 0.5f;
        float px2 = pr.x + pr.z * 0.5f, py2 = pr.y + pr.w * 0.5f;
        float pa = (px2 - px1) * (py2 - py1);
        unsigned lowp = 0xFFFFFFFFu - (unsigned)p;
#pragma unroll
        for (int t = 0; t < NO; ++t) {
            float iou = iou_pair(s_t[t][0], s_t[t][1], s_t[t][2], s_t[t][3], s_t[t][4],
                                 px1, py1, px2, py2, pa);
            unsigned long long k =
                (((unsigned long long)__float_as_uint(iou)) << 32) | (unsigned long long)lowp;
            if (k > key[t]) key[t] = k;
        }
    }
    int lane = tid & 63, wv = tid >> 6;
#pragma unroll
    for (int t = 0; t < NO; ++t) {
        unsigned long long k = key[t];
        for (int off = 32; off; off >>= 1) {
            unsigned long long o = __shfl_down(k, off);
            if (o > k) k = o;
        }
        if (lane == 0) s_k[wv][t] = k;
    }
    __syncthreads();
    if (tid < No) {
        unsigned long long m = s_k[0][tid];
#pragma unroll
        for (int w = 1; w < 4; ++w)
            if (s_k[w][tid] > m) m = s_k[w][tid];
        pkeys[((size_t)b * NMB + mb) * No + tid] = m;
    }
}

// Kernel B (main): per prior -> recompute best-truth match, combine match partials,
// apply override, CE via log-softmax from LDS-staged conf row, smooth-L1 for
// positives, write v=loss_c_hnm.
__global__ __launch_bounds__(TPB) void main_kernel(
    const float* __restrict__ loc, const float* __restrict__ conf,
    const float* __restrict__ dbox, const float* __restrict__ targets,
    const unsigned long long* __restrict__ pkeys,
    float* __restrict__ v, float* __restrict__ part_l, float* __restrict__ part_c,
    int* __restrict__ part_n, int Np, int C, int No, int nchunk) {
    extern __shared__ float s_conf[];  // TPB * C
    __shared__ float s_t[MAXNO][5];
    __shared__ float s_lab[MAXNO];
    __shared__ int s_ovr[MAXNO];
    __shared__ float s_red1[4];
    __shared__ float s_red2[4];
    __shared__ int s_redi[4];
    int b = blockIdx.y, chunk = blockIdx.x, tid = threadIdx.x;
    int p = chunk * TPB + tid;
    bool valid = p < Np;
    if (tid < No) {
        const float* tr = targets + ((size_t)b * No + tid) * 5;
        float x1 = tr[0], y1 = tr[1], x2 = tr[2], y2 = tr[3];
        s_t[tid][0] = x1; s_t[tid][1] = y1; s_t[tid][2] = x2; s_t[tid][3] = y2;
        s_t[tid][4] = (x2 - x1) * (y2 - y1);
        s_lab[tid] = tr[4];
        unsigned long long k = pkeys[((size_t)b * NMB + 0) * No + tid];
        for (int m = 1; m < NMB; ++m) {
            unsigned long long kk = pkeys[((size_t)b * NMB + m) * No + tid];
            if (kk > k) k = kk;
        }
        s_ovr[tid] = (int)(0xFFFFFFFFu - (unsigned)(k & 0xFFFFFFFFull));
    }
    int pbase = chunk * TPB;
    int cnt = Np - pbase;
    if (cnt > TPB) cnt = TPB;
    const float* cbase = conf + ((size_t)b * Np + (size_t)pbase) * C;
    for (int i = tid; i < cnt * C; i += TPB) s_conf[i] = cbase[i];
    __syncthreads();

    float lossl = 0.0f, posce = 0.0f;
    int npos = 0;
    if (valid) {
        float4 pr = *reinterpret_cast<const float4*>(dbox + (size_t)p * 4);
        float px1 = pr.x - pr.z * 0.5f, py1 = pr.y - pr.w * 0.5f;
        float px2 = pr.x + pr.z * 0.5f, py2 = pr.y + pr.w * 0.5f;
        float pa = (px2 - px1) * (py2 - py1);
        float bov = -1.0f;
        int bidx = 0;
        for (int t = 0; t < No; ++t) {
            float iou = iou_pair(s_t[t][0], s_t[t][1], s_t[t][2], s_t[t][3], s_t[t][4],
                                 px1, py1, px2, py2, pa);
            if (iou > bov) { bov = iou; bidx = t; }  // strict > : first occurrence
        }
        // override: ascending t, last wins (matches sequential duplicate scatter)
        for (int t = 0; t < No; ++t)
            if (s_ovr[t] == p) { bidx = t; bov = 2.0f; }
        int ct = (bov < 0.5f) ? 0 : ((int)s_lab[bidx] + 1);
        const float* crow = s_conf + (size_t)tid * C;
        float mx = crow[0];
        for (int j = 1; j < C; ++j) mx = fmaxf(mx, crow[j]);
        float s = 0.0f;
        for (int j = 0; j < C; ++j) s += expf(crow[j] - mx);
        float ce = logf(s) + mx - crow[ct];
        bool pos = ct > 0;
        v[(size_t)b * Np + p] = pos ? 0.0f : ce;
        if (pos) {
            posce = ce;
            npos = 1;
            float mx1 = s_t[bidx][0], my1 = s_t[bidx][1], mx2 = s_t[bidx][2], my2 = s_t[bidx][3];
            float gcx = ((mx1 + mx2) * 0.5f - pr.x) / (0.1f * pr.z);
            float gcy = ((my1 + my2) * 0.5f - pr.y) / (0.1f * pr.w);
            float gw = logf((mx2 - mx1) / pr.z) / 0.2f;
            float gh = logf((my2 - my1) / pr.w) / 0.2f;
            float4 l4 = *reinterpret_cast<const float4*>(loc + ((size_t)b * Np + p) * 4);
            lossl = sl1f(l4.x - gcx) + sl1f(l4.y - gcy) + sl1f(l4.z - gw) + sl1f(l4.w - gh);
        }
    }
    // single fused fixed-order block reduction (deterministic)
    float a1 = lossl, a2 = posce;
    int ni = npos;
    for (int off = 32; off; off >>= 1) {
        a1 += __shfl_down(a1, off);
        a2 += __shfl_down(a2, off);
        ni += __shfl_down(ni, off);
    }
    if ((tid & 63) == 0) {
        s_red1[tid >> 6] = a1;
        s_red2[tid >> 6] = a2;
        s_redi[tid >> 6] = ni;
    }
    __syncthreads();
    if (tid == 0) {
        part_l[(size_t)b * nchunk + chunk] = s_red1[0] + s_red1[1] + s_red1[2] + s_red1[3];
        part_c[(size_t)b * nchunk + chunk] = s_red2[0] + s_red2[1] + s_red2[2] + s_red2[3];
        part_n[(size_t)b * nchunk + chunk] = s_redi[0] + s_redi[1] + s_redi[2] + s_redi[3];
    }
}

// Kernel C: per row b -- radix-select the K-th largest float-bits threshold over v,
// then loss_c = posce + sum_{v > T} v + Krem * T.
__global__ __launch_bounds__(SELTPB) void select_kernel(
    const float* __restrict__ v, const float* __restrict__ pl,
    const float* __restrict__ pc, const int* __restrict__ pn,
    float* __restrict__ row_res, int Np, int nchunk, int negpos) {
    int b = blockIdx.x, tid = threadIdx.x;
    int lane = tid & 63, wv = tid >> 6;
    extern __shared__ unsigned sv[];  // Np
    __shared__ unsigned whist[SELWAVES][256];  // per-wave privatized hist (16 KB)
    __shared__ unsigned suf[257];
    __shared__ float s_f[SELWAVES];
    __shared__ int s_dig, s_acc;
    __shared__ float s_lossl, s_posce;
    __shared__ int s_np;

    if (wv == 0) {
        float a = 0.0f, c = 0.0f;
        int n = 0;
        for (int i = lane; i < nchunk; i += 64) {
            a += pl[(size_t)b * nchunk + i];
            c += pc[(size_t)b * nchunk + i];
            n += pn[(size_t)b * nchunk + i];
        }
        for (int off = 32; off; off >>= 1) {
            a += __shfl_down(a, off);
            c += __shfl_down(c, off);
            n += __shfl_down(n, off);
        }
        if (lane == 0) { s_lossl = a; s_posce = c; s_np = n; }
    }
    {
        const float4* v4 = reinterpret_cast<const float4*>(v + (size_t)b * Np);
        int n4 = Np >> 2;
        for (int i = tid; i < n4; i += SELTPB) {
            float4 f = v4[i];
            uint4 u;
            u.x = __float_as_uint(f.x); u.y = __float_as_uint(f.y);
            u.z = __float_as_uint(f.z); u.w = __float_as_uint(f.w);
            *reinterpret_cast<uint4*>(&sv[i << 2]) = u;
        }
        for (int i = (n4 << 2) + tid; i < Np; i += SELTPB)
            sv[i] = __float_as_uint(v[(size_t)b * Np + i]);
    }
    __syncthreads();
    int npos = s_np;
    int K = npos * negpos;
    if (K > Np) K = Np;
    float lossc = s_posce;
    if (K > 0) {
        unsigned prefix = 0;
        int Krem = K;
        for (int shift = 24; shift >= 0; shift -= 8) {
            for (int i = tid; i < SELWAVES * 256; i += SELTPB)
                (&whist[0][0])[i] = 0;
            __syncthreads();
            for (int i = tid; i < Np; i += SELTPB) {
                unsigned u = sv[i];
                bool match = (shift == 24) || ((u >> (shift + 8)) == (prefix >> (shift + 8)));
                if (match) atomicAdd(&whist[wv][(u >> shift) & 0xFFu], 1u);
            }
            __syncthreads();
            if (tid < 256) {
                unsigned t = 0;
                for (int w = 0; w < SELWAVES; ++w) t += whist[w][tid];
                suf[tid] = t;
            }
            if (tid == 0) suf[256] = 0;
            __syncthreads();
            for (int off = 1; off < 256; off <<= 1) {
                unsigned add = 0;
                if (tid < 256 && tid + off < 256) add = suf[tid + off];
                __syncthreads();
                if (tid < 256) suf[tid] += add;
                __syncthreads();
            }
            if (tid < 256) {
                unsigned S = suf[tid];
                unsigned Snext = suf[tid + 1];
                if ((int)S >= Krem && (int)Snext < Krem) { s_dig = tid; s_acc = (int)Snext; }
            }
            __syncthreads();
            prefix |= ((unsigned)s_dig) << shift;
            Krem -= s_acc;
            __syncthreads();
        }
        float sum_gt = 0.0f;
        for (int i = tid; i < Np; i += SELTPB) {
            unsigned u = sv[i];
            if (u > prefix) sum_gt += __uint_as_float(u);
        }
        for (int off = 32; off; off >>= 1) sum_gt += __shfl_down(sum_gt, off);
        if (lane == 0) s_f[wv] = sum_gt;
        __syncthreads();
        if (tid == 0) {
            float t = 0.0f;
            for (int w = 0; w < SELWAVES; ++w) t += s_f[w];
            lossc += t + (float)Krem * __uint_as_float(prefix);
        }
    }
    if (tid == 0) {
        row_res[(size_t)b * 3 + 0] = s_lossl;
        row_res[(size_t)b * 3 + 1] = lossc;
        row_res[(size_t)b * 3 + 2] = (float)npos;
    }
}

__global__ __launch_bounds__(TPB) void finalize_kernel(
    const float* __restrict__ row_res, float* __restrict__ out, int B) {
    int tid = threadIdx.x;
    float l = 0, c = 0, n = 0;
    for (int i = tid; i < B; i += TPB) {
        l += row_res[(size_t)i * 3 + 0];
        c += row_res[(size_t)i * 3 + 1];
        n += row_res[(size_t)i * 3 + 2];
    }
    __shared__ float sl[4], sc[4], sn[4];
    for (int off = 32; off; off >>= 1) {
        l += __shfl_down(l, off);
        c += __shfl_down(c, off);
        n += __shfl_down(n, off);
    }
    int lane = tid & 63, w = tid >> 6;
    if (lane == 0) { sl[w] = l; sc[w] = c; sn[w] = n; }
    __syncthreads();
    if (tid == 0) {
        l = sl[0] + sl[1] + sl[2] + sl[3];
        c = sc[0] + sc[1] + sc[2] + sc[3];
        n = sn[0] + sn[1] + sn[2] + sn[3];
        out[0] = l / n;
        out[1] = c / n;
    }
}

extern "C" void kernel_launch(void* const* d_in, const int* in_sizes, int n_in,
                              void* d_out, int out_size, void* d_ws, size_t ws_size,
                              hipStream_t stream) {
    const float* loc = (const float*)d_in[0];
    const float* conf = (const float*)d_in[1];
    const float* dbox = (const float*)d_in[2];
    const float* targets = (const float*)d_in[3];

    int Np = in_sizes[2] / 4;
    int B = in_sizes[0] / (Np * 4);
    int C = in_sizes[1] / (B * Np);
    int No = in_sizes[3] / (B * 5);
    int nchunk = (Np + TPB - 1) / TPB;

    char* w = (char*)d_ws;
    unsigned long long* pkeys = (unsigned long long*)w;
    w += (size_t)B * NMB * No * sizeof(unsigned long long);
    float* v = (float*)w;
    w += (size_t)B * Np * sizeof(float);
    float* part_l = (float*)w;
    w += (size_t)B * nchunk * sizeof(float);
    float* part_c = (float*)w;
    w += (size_t)B * nchunk * sizeof(float);
    int* part_n = (int*)w;
    w += (size_t)B * nchunk * sizeof(int);
    float* row_res = (float*)w;

    dim3 mgrid(NMB, B);
    if (No == 16)
        match_partial_kernel<16><<<mgrid, 256, 0, stream>>>(dbox, targets, pkeys, Np, No);
    else
        match_partial_kernel<MAXNO><<<mgrid, 256, 0, stream>>>(dbox, targets, pkeys, Np, No);

    dim3 grid(nchunk, B);
    size_t lds_main = (size_t)TPB * C * sizeof(float);
    main_kernel<<<grid, TPB, lds_main, stream>>>(loc, conf, dbox, targets, pkeys,
                                                 v, part_l, part_c, part_n, Np, C, No, nchunk);
    select_kernel<<<B, SELTPB, (size_t)Np * sizeof(float), stream>>>(v, part_l, part_c, part_n,
                                                                     row_res, Np, nchunk, 3);
    finalize_kernel<<<1, TPB, 0, stream>>>(row_res, (float*)d_out, B);
}